// Round 20
// baseline (99.747 us; speedup 1.0000x reference)
//
#include <hip/hip_runtime.h>
#include <math.h>

#define NB       1025
#define M        1024      // half-length complex FFT size
#define FFTN     2048
#define HOP      512
#define NFRAMES  4000
#define BATCH    4
#define OUT_T    2047488   // (F-1)*hop + N - 2*half
#define R_HOPS   8
#define NPAIR    251       // pairs/batch; pair p -> regions 2p, 2p+1 (501 = phantom)
#define NWG      (BATCH * NPAIR)   // 1004
#define PI_F     3.14159265358979323846f

// Intra-wave LDS write->read fence (cross-lane deps the compiler can't see).
// No block barrier, no vmcnt drain. Rule #18: sched_barrier after the wait.
#define WAVE_WAIT()                                            \
    do {                                                       \
        asm volatile("s_waitcnt lgkmcnt(0)" ::: "memory");     \
        __builtin_amdgcn_sched_barrier(0);                     \
    } while (0)

__device__ __forceinline__ float2 cmul(float2 a, float2 b) {
    return make_float2(a.x*b.x - a.y*b.y, a.x*b.y + a.y*b.x);
}
__device__ __forceinline__ float4 cmul4(float4 v, float2 w) {
    return make_float4(v.x*w.x - v.y*w.y, v.x*w.y + v.y*w.x,
                       v.z*w.x - v.w*w.y, v.z*w.y + v.w*w.x);
}
__device__ __forceinline__ float4 f4add(float4 a, float4 b){ return make_float4(a.x+b.x, a.y+b.y, a.z+b.z, a.w+b.w); }
__device__ __forceinline__ float4 f4sub(float4 a, float4 b){ return make_float4(a.x-b.x, a.y-b.y, a.z-b.z, a.w-b.w); }
__device__ __forceinline__ float4 f4addi(float4 a, float4 b){ return make_float4(a.x-b.y, a.y+b.x, a.z-b.w, a.w+b.z); } // a + i*b per half
__device__ __forceinline__ float4 f4subi(float4 a, float4 b){ return make_float4(a.x+b.y, a.y-b.x, a.z+b.w, a.w-b.z); } // a - i*b per half

// float4 bank-group swizzle on LOCAL (256-entry) index — stays in [0,256)
__device__ __forceinline__ int SW4(int i) { return i ^ ((i >> 3) & 7); }

// window_sumsquare at trimmed position p (boundary path, <=4 terms)
__device__ __forceinline__ float wsq_at(int p) {
    int u  = p + FFTN / 2;
    int fm = u >> 9;
    int n0 = u & 511;
    float wsq = 0.f;
    #pragma unroll
    for (int jj = 0; jj < 4; ++jj) {
        int fr = fm - jj;
        if (fr >= 0 && fr < NFRAMES) {
            int n = n0 + (jj << 9);
            float sw = __sinf((PI_F / (float)FFTN) * (float)n);
            float w  = sw * sw;
            wsq += w * w;
        }
    }
    const float tiny = 1.17549435e-38f;
    return (wsq > tiny) ? wsq : 1.0f;
}
__device__ __forceinline__ float invw_at(int p, bool edge) {
    if (edge && (p < 512 || p >= OUT_T - 512)) return 1.0f / wsq_at(p);
    return (2.0f / 3.0f);
}

// Wave-private 256-pt Stockham stage (64 butterflies = 64 lanes, stride 64).
template<int ST>
__device__ __forceinline__ void stage256(const float4* __restrict__ src,
                                         float4* __restrict__ dst, int l, float2 w1) {
    const int Ns = 1 << (2 * ST);
    float4 v0 = src[SW4(l)];
    float4 v1 = src[SW4(l + 64)];
    float4 v2 = src[SW4(l + 128)];
    float4 v3 = src[SW4(l + 192)];
    float2 w2 = cmul(w1, w1);
    float2 w3 = cmul(w2, w1);
    v1 = cmul4(v1, w1); v2 = cmul4(v2, w2); v3 = cmul4(v3, w3);
    float4 t0 = f4add(v0, v2), t1 = f4sub(v0, v2);
    float4 t2 = f4add(v1, v3), t3 = f4sub(v1, v3);
    int jm = l & (Ns - 1);
    int idxD = ((l >> (2 * ST)) << (2 * ST + 2)) + jm;
    dst[SW4(idxD         )] = f4add(t0, t2);
    dst[SW4(idxD +     Ns)] = f4addi(t1, t3);
    dst[SW4(idxD + 2 * Ns)] = f4sub(t0, t2);
    dst[SW4(idxD + 3 * Ns)] = f4subi(t1, t3);
}

// Four-step ISTFT: 1024 = 4(waves) x 256(wave-private Stockham).
// FFT stages are wave-synchronous (WAVE_WAIT only); 2 block barriers/pair.
__global__ __launch_bounds__(256) void istft_ws_kernel(
    const float* __restrict__ sr, const float* __restrict__ si,
    float* __restrict__ out)
{
    __shared__ float4 bufA[M];   // 16 KB; wave w owns [w*256, w*256+256)
    __shared__ float4 bufB[M];   // 16 KB

    // T1 bijective XCD swizzle (neutral but kept; NWG=1004, 8 XCDs)
    int blk;
    {
        const int o   = blockIdx.x;
        const int xcd = o & 7, k = o >> 3;
        const int q = NWG / 8, r = NWG % 8;   // 125, 4
        blk = (xcd < r ? xcd * (q + 1) : r * (q + 1) + (xcd - r) * q) + k;
    }

    const int b    = blk / NPAIR;
    const int pr   = blk - b * NPAIR;
    const int regA = 2 * pr;
    const int s0hA = regA * R_HOPS;
    const int s0hB = s0hA + R_HOPS;
    const int tid  = threadIdx.x;
    const int l    = tid & 63;          // lane: butterfly index in 256-FFT
    const int wv   = tid >> 6;          // wave: subsequence k = 4*k1 + wv
    const bool edgeA = (regA == 0) || (regA == 500);
    const bool edgeB = (regA + 1 == 500);   // region 501 phantom: stores all OOB

    float4* __restrict__ wA = bufA + wv * 256;
    float4* __restrict__ wB = bufB + wv * 256;

    // ---- per-thread precompute ----
    // pack twiddles at bins k_e = 4*(l + 64e) + wv
    float2 tw_pack[4];
    #pragma unroll
    for (int e = 0; e < 4; ++e) {
        int k = 4 * (l + 64 * e) + wv;
        float s, c;
        __sincosf(PI_F * (float)k * (1.0f / 1024.0f), &s, &c);
        tw_pack[e] = make_float2(c, s);
    }
    // wave-private stage twiddles (256-domain): ST=1..3, Ns=4,16,64
    float2 w1s[3];
    #pragma unroll
    for (int st = 1; st <= 3; ++st) {
        int Ns = 1 << (2 * st);
        int jm = l & (Ns - 1);
        float ang = (0.5f * PI_F / (float)Ns) * (float)jm;
        float s1, c1;
        __sincosf(ang, &s1, &c1);
        w1s[st-1] = make_float2(c1, s1);
    }
    // gather twiddles w1024^{m*w}, m = tid
    float2 wg1, wg2, wg3;
    {
        float s, c;
        __sincosf((PI_F / 512.f) * (float)tid, &s, &c);        wg1 = make_float2(c, s);
        __sincosf((PI_F / 512.f) * (float)(2 * tid), &s, &c);  wg2 = make_float2(c, s);
        __sincosf((PI_F / 512.f) * (float)(3 * tid), &s, &c);  wg3 = make_float2(c, s);
    }
    float wreg[4][2];                    // hann(t)^2 / M at n = tid + q*256
    #pragma unroll
    for (int q = 0; q < 4; ++q) {
        int n = tid + q * 256;
        #pragma unroll
        for (int h = 0; h < 2; ++h) {
            int t = 2 * n + h;
            float swv = __sinf((PI_F / (float)FFTN) * (float)t);
            wreg[q][h] = swv * swv * (1.0f / 1024.0f);
        }
    }

    float2 AccA[R_HOPS], AccB[R_HOPS];
    #pragma unroll
    for (int s = 0; s < R_HOPS; ++s) {
        AccA[s] = make_float2(0.f, 0.f);
        AccB[s] = make_float2(0.f, 0.f);
    }

    // ---- preload it=0 spectra (clamped) into the working registers ----
    float a1r[4], a1i[4], b1r[4], b1i[4];
    float a2r[4], a2i[4], b2r[4], b2i[4];
    {
        int fA0 = s0hA - 3; fA0 = fA0 < 0 ? 0 : (fA0 > NFRAMES-1 ? NFRAMES-1 : fA0);
        int fB0 = s0hB - 3; fB0 = fB0 < 0 ? 0 : (fB0 > NFRAMES-1 ? NFRAMES-1 : fB0);
        const size_t fbA = ((size_t)b * NFRAMES + fA0) * NB;
        const size_t fbB = ((size_t)b * NFRAMES + fB0) * NB;
        #pragma unroll
        for (int e = 0; e < 4; ++e) {
            int k  = 4 * (l + 64 * e) + wv;
            int mk = 1024 - k;
            a1r[e] = sr[fbA + k];  a1i[e] = si[fbA + k];
            b1r[e] = sr[fbA + mk]; b1i[e] = si[fbA + mk];
            a2r[e] = sr[fbB + k];  a2i[e] = si[fbB + k];
            b2r[e] = sr[fbB + mk]; b2i[e] = si[fbB + mk];
        }
    }

    #pragma unroll
    for (int it = 0; it < 11; ++it) {
        const int fA = s0hA - 3 + it;
        const int fB = s0hB - 3 + it;
        const bool vA = (fA >= 0) && (fA < NFRAMES);
        const bool vB = (fB >= 0) && (fB < NFRAMES);
        if (!vA && !vB) continue;       // block-uniform (trailing only)

        // ---- pack (Hermitian fold, both frames) + stage-0 -> wave region ----
        {
            float4 z[4];
            #pragma unroll
            for (int e = 0; e < 4; ++e) {
                int k = 4 * (l + 64 * e) + wv;
                float ar = a1r[e], ai = a1i[e], br = b1r[e], bi = b1i[e];
                float cr = a2r[e], ci = a2i[e], dr = b2r[e], di = b2i[e];
                if (k == 0) { ai = 0.f; bi = 0.f; ci = 0.f; di = 0.f; }
                float2 t = tw_pack[e];
                float Er = 0.5f*(ar+br), Ei = 0.5f*(ai-bi), Dr = 0.5f*(ar-br), Di = 0.5f*(ai+bi);
                float Or = Dr*t.x - Di*t.y, Oi = Dr*t.y + Di*t.x;
                float Fr = 0.5f*(cr+dr), Fi = 0.5f*(ci-di), Gr = 0.5f*(cr-dr), Gi = 0.5f*(ci+di);
                float Pr = Gr*t.x - Gi*t.y, Pi = Gr*t.y + Gi*t.x;
                z[e] = make_float4(Er - Oi, Ei + Or, Fr - Pi, Fi + Pr);
            }
            float4 t0 = f4add(z[0], z[2]), t1 = f4sub(z[0], z[2]);
            float4 t2 = f4add(z[1], z[3]), t3 = f4sub(z[1], z[3]);
            wA[SW4(4*l    )] = f4add(t0, t2);
            wA[SW4(4*l + 1)] = f4addi(t1, t3);
            wA[SW4(4*l + 2)] = f4sub(t0, t2);
            wA[SW4(4*l + 3)] = f4subi(t1, t3);
        }

        // ---- issue it+1's loads into the SAME (now dead) registers ----
        // They drain at the pre-gather __syncthreads: hidden under 3 stages.
        if (it < 10) {
            int fAn = fA + 1; fAn = fAn < 0 ? 0 : (fAn > NFRAMES-1 ? NFRAMES-1 : fAn);
            int fBn = fB + 1; fBn = fBn < 0 ? 0 : (fBn > NFRAMES-1 ? NFRAMES-1 : fBn);
            const size_t fbA = ((size_t)b * NFRAMES + fAn) * NB;
            const size_t fbB = ((size_t)b * NFRAMES + fBn) * NB;
            #pragma unroll
            for (int e = 0; e < 4; ++e) {
                int k  = 4 * (l + 64 * e) + wv;
                int mk = 1024 - k;
                a1r[e] = sr[fbA + k];  a1i[e] = si[fbA + k];
                b1r[e] = sr[fbA + mk]; b1i[e] = si[fbA + mk];
                a2r[e] = sr[fbB + k];  a2i[e] = si[fbB + k];
                b2r[e] = sr[fbB + mk]; b2i[e] = si[fbB + mk];
            }
        }

        // ---- wave-private 256-pt Stockham (NO block barriers) ----
        WAVE_WAIT();
        stage256<1>(wA, wB, l, w1s[0]);
        WAVE_WAIT();
        stage256<2>(wB, wA, l, w1s[1]);
        WAVE_WAIT();
        stage256<3>(wA, wB, l, w1s[2]);   // S_w in natural order in wB

        __syncthreads();   // all waves' S ready (also drains this wave's LDS)

        // ---- cross-wave 4-pt combine + window + accumulate (m = tid) ----
        {
            float4 T0 = bufB[        SW4(tid)];
            float4 T1 = cmul4(bufB[256 + SW4(tid)], wg1);
            float4 T2 = cmul4(bufB[512 + SW4(tid)], wg2);
            float4 T3 = cmul4(bufB[768 + SW4(tid)], wg3);
            float4 t0 = f4add(T0, T2), t1 = f4sub(T0, T2);
            float4 t2 = f4add(T1, T3), t3 = f4sub(T1, T3);
            float4 g[4];
            g[0] = f4add(t0, t2);    // n = tid
            g[1] = f4addi(t1, t3);   // n = tid+256
            g[2] = f4sub(t0, t2);    // n = tid+512
            g[3] = f4subi(t1, t3);   // n = tid+768
            if (vA) {
                #pragma unroll
                for (int q = 0; q < 4; ++q) {
                    const int s = it - 3 + q;          // compile-time
                    if (s >= 0 && s < R_HOPS) {
                        AccA[s].x += g[q].x * wreg[q][0];
                        AccA[s].y += g[q].y * wreg[q][1];
                    }
                }
            }
            if (vB) {
                #pragma unroll
                for (int q = 0; q < 4; ++q) {
                    const int s = it - 3 + q;
                    if (s >= 0 && s < R_HOPS) {
                        AccB[s].x += g[q].z * wreg[q][0];
                        AccB[s].y += g[q].w * wreg[q][1];
                    }
                }
            }
        }
        __syncthreads();   // gather reads of bufB done before next st1 writes
    }

    // ---- epilogue: divide by wsq, coalesced single store per sample ----
    float* outb = out + (size_t)b * OUT_T;
    {
        const int base_u = s0hA * HOP;
        #pragma unroll
        for (int s = 0; s < R_HOPS; ++s) {
            int i2 = tid + 256 * s;
            int p0 = base_u + 2 * i2 - FFTN / 2;
            int p1 = p0 + 1;
            if ((unsigned)p0 < (unsigned)OUT_T) outb[p0] = AccA[s].x * invw_at(p0, edgeA);
            if ((unsigned)p1 < (unsigned)OUT_T) outb[p1] = AccA[s].y * invw_at(p1, edgeA);
        }
    }
    {
        const int base_u = s0hB * HOP;
        #pragma unroll
        for (int s = 0; s < R_HOPS; ++s) {
            int i2 = tid + 256 * s;
            int p0 = base_u + 2 * i2 - FFTN / 2;
            int p1 = p0 + 1;
            if ((unsigned)p0 < (unsigned)OUT_T) outb[p0] = AccB[s].x * invw_at(p0, edgeB);
            if ((unsigned)p1 < (unsigned)OUT_T) outb[p1] = AccB[s].y * invw_at(p1, edgeB);
        }
    }
}

extern "C" void kernel_launch(void* const* d_in, const int* in_sizes, int n_in,
                              void* d_out, int out_size, void* d_ws, size_t ws_size,
                              hipStream_t stream) {
    const float* sr = (const float*)d_in[0];
    const float* si = (const float*)d_in[1];
    float* out = (float*)d_out;
    istft_ws_kernel<<<NWG, 256, 0, stream>>>(sr, si, out);
}

// Round 21
// 56.747 us; speedup vs baseline: 1.7578x; 1.7578x over previous
//
#include <hip/hip_runtime.h>
#include <math.h>

#define NB       1025
#define M        1024      // half-length complex FFT size
#define FFTN     2048
#define HOP      512
#define NFRAMES  4000
#define BATCH    4
#define OUT_T    2047488   // (F-1)*hop + N - 2*half
#define R_HOPS   8
#define NPAIR    251       // pairs/batch; pair p -> regions 2p, 2p+1 (501 = phantom)
#define NWG      (BATCH * NPAIR)   // 1004
#define PI_F     3.14159265358979323846f

__device__ __forceinline__ float2 cmul(float2 a, float2 b) {
    return make_float2(a.x*b.x - a.y*b.y, a.x*b.y + a.y*b.x);
}
__device__ __forceinline__ float4 cmul4(float4 v, float2 w) {
    return make_float4(v.x*w.x - v.y*w.y, v.x*w.y + v.y*w.x,
                       v.z*w.x - v.w*w.y, v.z*w.y + v.w*w.x);
}
__device__ __forceinline__ float4 f4add(float4 a, float4 b){ return make_float4(a.x+b.x, a.y+b.y, a.z+b.z, a.w+b.w); }
__device__ __forceinline__ float4 f4sub(float4 a, float4 b){ return make_float4(a.x-b.x, a.y-b.y, a.z-b.z, a.w-b.w); }
__device__ __forceinline__ float4 f4addi(float4 a, float4 b){ return make_float4(a.x-b.y, a.y+b.x, a.z-b.w, a.w+b.z); } // a + i*b per half
__device__ __forceinline__ float4 f4subi(float4 a, float4 b){ return make_float4(a.x+b.y, a.y-b.x, a.z+b.w, a.w-b.z); } // a - i*b per half

// float4 bank-group swizzle (R14-verified: conflicts 4.2M -> 1.5M)
__device__ __forceinline__ int SW4(int i) { return i ^ ((i >> 3) & 7); }

// window_sumsquare at trimmed position p (boundary path, <=4 terms)
__device__ __forceinline__ float wsq_at(int p) {
    int u  = p + FFTN / 2;
    int fm = u >> 9;
    int n0 = u & 511;
    float wsq = 0.f;
    #pragma unroll
    for (int jj = 0; jj < 4; ++jj) {
        int fr = fm - jj;
        if (fr >= 0 && fr < NFRAMES) {
            int n = n0 + (jj << 9);
            float sw = __sinf((PI_F / (float)FFTN) * (float)n);
            float w  = sw * sw;
            wsq += w * w;
        }
    }
    const float tiny = 1.17549435e-38f;
    return (wsq > tiny) ? wsq : 1.0f;
}
__device__ __forceinline__ float invw_at(int p, bool edge) {
    if (edge && (p < 512 || p >= OUT_T - 512)) return 1.0f / wsq_at(p);
    return (2.0f / 3.0f);
}

// Out-of-place Stockham stage on paired-frame float4 elements.
template<int ST>
__device__ __forceinline__ void stage4x(const float4* __restrict__ src,
                                        float4* __restrict__ dst, int j, float2 w1) {
    const int Ns = 1 << (2 * ST);
    float4 v0 = src[SW4(j)];
    float4 v1 = src[SW4(j + 256)];
    float4 v2 = src[SW4(j + 512)];
    float4 v3 = src[SW4(j + 768)];
    float2 w2 = cmul(w1, w1);
    float2 w3 = cmul(w2, w1);
    v1 = cmul4(v1, w1); v2 = cmul4(v2, w2); v3 = cmul4(v3, w3);
    float4 t0 = f4add(v0, v2), t1 = f4sub(v0, v2);
    float4 t2 = f4add(v1, v3), t3 = f4sub(v1, v3);
    int jm = j & (Ns - 1);
    int idxD = ((j >> (2 * ST)) << (2 * ST + 2)) + jm;
    dst[SW4(idxD         )] = f4add(t0, t2);
    dst[SW4(idxD +     Ns)] = f4addi(t1, t3);
    dst[SW4(idxD + 2 * Ns)] = f4sub(t0, t2);
    dst[SW4(idxD + 3 * Ns)] = f4subi(t1, t3);
}

__device__ __forceinline__ void load_spec(const float* __restrict__ sr,
                                          const float* __restrict__ si,
                                          int b, int f, int j,
                                          float* car, float* cai,
                                          float* cbr, float* cbi) {
    const size_t fb = ((size_t)b * NFRAMES + f) * NB;
    const float* __restrict__ xr = sr + fb;
    const float* __restrict__ xi = si + fb;
    #pragma unroll
    for (int kk = 0; kk < 4; ++kk) {
        int k  = j + kk * 256;
        int mk = M - k;
        car[kk] = xr[k];  cai[kk] = xi[k];
        cbr[kk] = xr[mk]; cbi[kk] = xi[mk];
    }
}

// Hermitian pack (both frames) + Stockham stage 0 fused -> float4 LDS.
__device__ __forceinline__ void pack2_st0(float4* __restrict__ dst, int j,
                                          const float2* twp,
                                          const float* a1r, const float* a1i,
                                          const float* b1r, const float* b1i,
                                          const float* a2r, const float* a2i,
                                          const float* b2r, const float* b2i) {
    float4 z[4];
    #pragma unroll
    for (int kk = 0; kk < 4; ++kk) {
        float ar = a1r[kk], ai = a1i[kk], br = b1r[kk], bi = b1i[kk];
        float cr = a2r[kk], ci = a2i[kk], dr = b2r[kk], di = b2i[kk];
        if (kk == 0 && j == 0) { ai = 0.f; bi = 0.f; ci = 0.f; di = 0.f; }
        float2 t = twp[kk];
        float Er = 0.5f*(ar+br), Ei = 0.5f*(ai-bi), Dr = 0.5f*(ar-br), Di = 0.5f*(ai+bi);
        float Or = Dr*t.x - Di*t.y, Oi = Dr*t.y + Di*t.x;
        float Fr = 0.5f*(cr+dr), Fi = 0.5f*(ci-di), Gr = 0.5f*(cr-dr), Gi = 0.5f*(ci+di);
        float Pr = Gr*t.x - Gi*t.y, Pi = Gr*t.y + Gi*t.x;
        z[kk] = make_float4(Er - Oi, Ei + Or, Fr - Pi, Fi + Pr);
    }
    float4 t0 = f4add(z[0], z[2]), t1 = f4sub(z[0], z[2]);
    float4 t2 = f4add(z[1], z[3]), t3 = f4sub(z[1], z[3]);
    dst[SW4(4*j    )] = f4add(t0, t2);
    dst[SW4(4*j + 1)] = f4addi(t1, t3);
    dst[SW4(4*j + 2)] = f4sub(t0, t2);
    dst[SW4(4*j + 3)] = f4subi(t1, t3);
}

// Two regions per block; paired frames share every LDS access; register
// accumulators; prefetch issued AFTER the stage-3 barrier so the loads
// cross ZERO barriers (no vmcnt drain) and hide under st4+accumulate.
__global__ __launch_bounds__(256) void istft_pair_kernel(
    const float* __restrict__ sr, const float* __restrict__ si,
    float* __restrict__ out)
{
    __shared__ float4 buf0[M];   // 16 KB
    __shared__ float4 buf1[M];   // 16 KB

    // T1 bijective XCD swizzle (neutral but kept; NWG=1004, 8 XCDs)
    int blk;
    {
        const int o   = blockIdx.x;
        const int xcd = o & 7, k = o >> 3;
        const int q = NWG / 8, r = NWG % 8;   // 125, 4
        blk = (xcd < r ? xcd * (q + 1) : r * (q + 1) + (xcd - r) * q) + k;
    }

    const int b    = blk / NPAIR;
    const int pr   = blk - b * NPAIR;
    const int regA = 2 * pr;
    const int s0hA = regA * R_HOPS;
    const int s0hB = s0hA + R_HOPS;
    const int j    = threadIdx.x;
    const bool edgeA = (regA == 0) || (regA == 500);
    const bool edgeB = (regA + 1 == 500);   // region 501 phantom: stores all OOB

    // ---- per-block precompute ----
    float2 tw_pack[4];
    #pragma unroll
    for (int kk = 0; kk < 4; ++kk) {
        int k = j + kk * 256;
        float s, c;
        __sincosf(PI_F * (float)k * (1.0f / (float)M), &s, &c);
        tw_pack[kk] = make_float2(c, s);
    }
    float2 w1s[4];
    #pragma unroll
    for (int st = 1; st <= 4; ++st) {
        int Ns = 1 << (2 * st);
        int jm = j & (Ns - 1);
        float ang = (0.5f * PI_F / (float)Ns) * (float)jm;
        float s1, c1;
        __sincosf(ang, &s1, &c1);
        w1s[st-1] = make_float2(c1, s1);
    }
    float wreg[4][2];
    #pragma unroll
    for (int q = 0; q < 4; ++q) {
        int n = j + q * 256;
        #pragma unroll
        for (int h = 0; h < 2; ++h) {
            int t = 2 * n + h;
            float swv = __sinf((PI_F / (float)FFTN) * (float)t);
            wreg[q][h] = swv * swv * (1.0f / 1024.0f);
        }
    }

    float2 AccA[R_HOPS], AccB[R_HOPS];
    #pragma unroll
    for (int s = 0; s < R_HOPS; ++s) {
        AccA[s] = make_float2(0.f, 0.f);
        AccB[s] = make_float2(0.f, 0.f);
    }

    // ---- preload it=0 spectra (clamped) ----
    float a1r[4], a1i[4], b1r[4], b1i[4];
    float a2r[4], a2i[4], b2r[4], b2i[4];
    {
        int fA0 = s0hA - 3; fA0 = fA0 < 0 ? 0 : (fA0 > NFRAMES-1 ? NFRAMES-1 : fA0);
        int fB0 = s0hB - 3; fB0 = fB0 < 0 ? 0 : (fB0 > NFRAMES-1 ? NFRAMES-1 : fB0);
        load_spec(sr, si, b, fA0, j, a1r, a1i, b1r, b1i);
        load_spec(sr, si, b, fB0, j, a2r, a2i, b2r, b2i);
    }

    #pragma unroll
    for (int it = 0; it < 11; ++it) {
        const int fA = s0hA - 3 + it;
        const int fB = s0hB - 3 + it;
        const bool vA = (fA >= 0) && (fA < NFRAMES);
        const bool vB = (fB >= 0) && (fB < NFRAMES);
        if (!vA && !vB) continue;           // block-uniform (trailing only)

        // pack consumes the spectra registers loaded last iteration
        pack2_st0(buf0, j, tw_pack, a1r, a1i, b1r, b1i, a2r, a2i, b2r, b2i);
        __syncthreads();
        stage4x<1>(buf0, buf1, j, w1s[0]);
        __syncthreads();
        stage4x<2>(buf1, buf0, j, w1s[1]);
        __syncthreads();
        stage4x<3>(buf0, buf1, j, w1s[2]);
        __syncthreads();

        // ---- prefetch it+1 NOW: crosses no barrier before its use in
        //      pack(it+1); latency hides under st4+accumulate below ----
        if (it < 10) {
            int fAn = fA + 1; fAn = fAn < 0 ? 0 : (fAn > NFRAMES-1 ? NFRAMES-1 : fAn);
            int fBn = fB + 1; fBn = fBn < 0 ? 0 : (fBn > NFRAMES-1 ? NFRAMES-1 : fBn);
            load_spec(sr, si, b, fAn, j, a1r, a1i, b1r, b1i);
            load_spec(sr, si, b, fBn, j, a2r, a2i, b2r, b2i);
        }

        // ---- stage 4 in registers + masked windowed accumulate ----
        {
            float4 v0 = buf1[SW4(j)];
            float4 v1 = buf1[SW4(j + 256)];
            float4 v2 = buf1[SW4(j + 512)];
            float4 v3 = buf1[SW4(j + 768)];
            float2 w1 = w1s[3];
            float2 w2 = cmul(w1, w1);
            float2 w3 = cmul(w2, w1);
            v1 = cmul4(v1, w1); v2 = cmul4(v2, w2); v3 = cmul4(v3, w3);
            float4 t0 = f4add(v0, v2), t1 = f4sub(v0, v2);
            float4 t2 = f4add(v1, v3), t3 = f4sub(v1, v3);
            float4 g[4];
            g[0] = f4add(t0, t2);    // n = j
            g[1] = f4addi(t1, t3);   // n = j+256
            g[2] = f4sub(t0, t2);    // n = j+512
            g[3] = f4subi(t1, t3);   // n = j+768
            if (vA) {
                #pragma unroll
                for (int q = 0; q < 4; ++q) {
                    const int s = it - 3 + q;          // compile-time
                    if (s >= 0 && s < R_HOPS) {
                        AccA[s].x += g[q].x * wreg[q][0];
                        AccA[s].y += g[q].y * wreg[q][1];
                    }
                }
            }
            if (vB) {
                #pragma unroll
                for (int q = 0; q < 4; ++q) {
                    const int s = it - 3 + q;
                    if (s >= 0 && s < R_HOPS) {
                        AccB[s].x += g[q].z * wreg[q][0];
                        AccB[s].y += g[q].w * wreg[q][1];
                    }
                }
            }
        }
        // NO trailing barrier (R16-verified ping-pong argument): next pack
        // writes buf0 only — its last readers (stage3) are behind the stage3
        // barrier; st4's buf1 reads complete before this thread reaches the
        // next pack barrier, which precedes stage1(it+1)'s buf1 writes.
    }

    // ---- epilogue: divide by wsq, coalesced single store per sample ----
    float* outb = out + (size_t)b * OUT_T;
    {
        const int base_u = s0hA * HOP;
        #pragma unroll
        for (int s = 0; s < R_HOPS; ++s) {
            int i2 = j + 256 * s;
            int p0 = base_u + 2 * i2 - FFTN / 2;
            int p1 = p0 + 1;
            if ((unsigned)p0 < (unsigned)OUT_T) outb[p0] = AccA[s].x * invw_at(p0, edgeA);
            if ((unsigned)p1 < (unsigned)OUT_T) outb[p1] = AccA[s].y * invw_at(p1, edgeA);
        }
    }
    {
        const int base_u = s0hB * HOP;
        #pragma unroll
        for (int s = 0; s < R_HOPS; ++s) {
            int i2 = j + 256 * s;
            int p0 = base_u + 2 * i2 - FFTN / 2;
            int p1 = p0 + 1;
            if ((unsigned)p0 < (unsigned)OUT_T) outb[p0] = AccB[s].x * invw_at(p0, edgeB);
            if ((unsigned)p1 < (unsigned)OUT_T) outb[p1] = AccB[s].y * invw_at(p1, edgeB);
        }
    }
}

extern "C" void kernel_launch(void* const* d_in, const int* in_sizes, int n_in,
                              void* d_out, int out_size, void* d_ws, size_t ws_size,
                              hipStream_t stream) {
    const float* sr = (const float*)d_in[0];
    const float* si = (const float*)d_in[1];
    float* out = (float*)d_out;
    istft_pair_kernel<<<NWG, 256, 0, stream>>>(sr, si, out);
}

// Round 22
// 50.069 us; speedup vs baseline: 1.9922x; 1.1334x over previous
//
#include <hip/hip_runtime.h>
#include <math.h>

#define NB       1025
#define M        1024      // half-length complex FFT size
#define FFTN     2048
#define HOP      512
#define NFRAMES  4000
#define BATCH    4
#define OUT_T    2047488   // (F-1)*hop + N - 2*half
#define R_HOPS   8
#define NPAIR    251       // pairs/batch; pair p -> regions 2p, 2p+1 (501 = phantom)
#define NWG      (BATCH * NPAIR)   // 1004
#define CHOPS    16        // combined region hops (2 regions)
#define PI_F     3.14159265358979323846f

__device__ __forceinline__ float2 cmul(float2 a, float2 b) {
    return make_float2(a.x*b.x - a.y*b.y, a.x*b.y + a.y*b.x);
}
__device__ __forceinline__ float4 cmul4(float4 v, float2 w) {
    return make_float4(v.x*w.x - v.y*w.y, v.x*w.y + v.y*w.x,
                       v.z*w.x - v.w*w.y, v.z*w.y + v.w*w.x);
}
__device__ __forceinline__ float4 f4add(float4 a, float4 b){ return make_float4(a.x+b.x, a.y+b.y, a.z+b.z, a.w+b.w); }
__device__ __forceinline__ float4 f4sub(float4 a, float4 b){ return make_float4(a.x-b.x, a.y-b.y, a.z-b.z, a.w-b.w); }
__device__ __forceinline__ float4 f4addi(float4 a, float4 b){ return make_float4(a.x-b.y, a.y+b.x, a.z-b.w, a.w+b.z); } // a + i*b per half
__device__ __forceinline__ float4 f4subi(float4 a, float4 b){ return make_float4(a.x+b.y, a.y-b.x, a.z+b.w, a.w-b.z); } // a - i*b per half

// float4 bank-group swizzle (R14-verified: conflicts 4.2M -> 1.5M)
__device__ __forceinline__ int SW4(int i) { return i ^ ((i >> 3) & 7); }

// window_sumsquare at trimmed position p (boundary path, <=4 terms)
__device__ __forceinline__ float wsq_at(int p) {
    int u  = p + FFTN / 2;
    int fm = u >> 9;
    int n0 = u & 511;
    float wsq = 0.f;
    #pragma unroll
    for (int jj = 0; jj < 4; ++jj) {
        int fr = fm - jj;
        if (fr >= 0 && fr < NFRAMES) {
            int n = n0 + (jj << 9);
            float sw = __sinf((PI_F / (float)FFTN) * (float)n);
            float w  = sw * sw;
            wsq += w * w;
        }
    }
    const float tiny = 1.17549435e-38f;
    return (wsq > tiny) ? wsq : 1.0f;
}
__device__ __forceinline__ float invw_at(int p, bool edge) {
    if (edge && (p < 512 || p >= OUT_T - 512)) return 1.0f / wsq_at(p);
    return (2.0f / 3.0f);
}

// Out-of-place Stockham stage on paired-frame float4 elements.
template<int ST>
__device__ __forceinline__ void stage4x(const float4* __restrict__ src,
                                        float4* __restrict__ dst, int j, float2 w1) {
    const int Ns = 1 << (2 * ST);
    float4 v0 = src[SW4(j)];
    float4 v1 = src[SW4(j + 256)];
    float4 v2 = src[SW4(j + 512)];
    float4 v3 = src[SW4(j + 768)];
    float2 w2 = cmul(w1, w1);
    float2 w3 = cmul(w2, w1);
    v1 = cmul4(v1, w1); v2 = cmul4(v2, w2); v3 = cmul4(v3, w3);
    float4 t0 = f4add(v0, v2), t1 = f4sub(v0, v2);
    float4 t2 = f4add(v1, v3), t3 = f4sub(v1, v3);
    int jm = j & (Ns - 1);
    int idxD = ((j >> (2 * ST)) << (2 * ST + 2)) + jm;
    dst[SW4(idxD         )] = f4add(t0, t2);
    dst[SW4(idxD +     Ns)] = f4addi(t1, t3);
    dst[SW4(idxD + 2 * Ns)] = f4sub(t0, t2);
    dst[SW4(idxD + 3 * Ns)] = f4subi(t1, t3);
}

__device__ __forceinline__ void load_spec(const float* __restrict__ sr,
                                          const float* __restrict__ si,
                                          int b, int f, int j,
                                          float* car, float* cai,
                                          float* cbr, float* cbi) {
    const size_t fb = ((size_t)b * NFRAMES + f) * NB;
    const float* __restrict__ xr = sr + fb;
    const float* __restrict__ xi = si + fb;
    #pragma unroll
    for (int kk = 0; kk < 4; ++kk) {
        int k  = j + kk * 256;
        int mk = M - k;
        car[kk] = xr[k];  cai[kk] = xi[k];
        cbr[kk] = xr[mk]; cbi[kk] = xi[mk];
    }
}

// Hermitian pack (both frames) + Stockham stage 0 fused -> float4 LDS.
__device__ __forceinline__ void pack2_st0(float4* __restrict__ dst, int j,
                                          const float2* twp,
                                          const float* a1r, const float* a1i,
                                          const float* b1r, const float* b1i,
                                          const float* a2r, const float* a2i,
                                          const float* b2r, const float* b2i) {
    float4 z[4];
    #pragma unroll
    for (int kk = 0; kk < 4; ++kk) {
        float ar = a1r[kk], ai = a1i[kk], br = b1r[kk], bi = b1i[kk];
        float cr = a2r[kk], ci = a2i[kk], dr = b2r[kk], di = b2i[kk];
        if (kk == 0 && j == 0) { ai = 0.f; bi = 0.f; ci = 0.f; di = 0.f; }
        float2 t = twp[kk];
        float Er = 0.5f*(ar+br), Ei = 0.5f*(ai-bi), Dr = 0.5f*(ar-br), Di = 0.5f*(ai+bi);
        float Or = Dr*t.x - Di*t.y, Oi = Dr*t.y + Di*t.x;
        float Fr = 0.5f*(cr+dr), Fi = 0.5f*(ci-di), Gr = 0.5f*(cr-dr), Gi = 0.5f*(ci+di);
        float Pr = Gr*t.x - Gi*t.y, Pi = Gr*t.y + Gi*t.x;
        z[kk] = make_float4(Er - Oi, Ei + Or, Fr - Pi, Fi + Pr);
    }
    float4 t0 = f4add(z[0], z[2]), t1 = f4sub(z[0], z[2]);
    float4 t2 = f4add(z[1], z[3]), t3 = f4sub(z[1], z[3]);
    dst[SW4(4*j    )] = f4add(t0, t2);
    dst[SW4(4*j + 1)] = f4addi(t1, t3);
    dst[SW4(4*j + 2)] = f4sub(t0, t2);
    dst[SW4(4*j + 3)] = f4subi(t1, t3);
}

// Two regions per block with a UNIFIED 16-hop register accumulator:
// the 19 distinct frames are FFT'd exactly once each (10 float4-paired
// iterations, last B-slot phantom) — removes the 3 duplicate frame FFTs
// the split-accumulator version paid per block.
__global__ __launch_bounds__(256) void istft_pair_kernel(
    const float* __restrict__ sr, const float* __restrict__ si,
    float* __restrict__ out)
{
    __shared__ float4 buf0[M];   // 16 KB
    __shared__ float4 buf1[M];   // 16 KB

    // T1 bijective XCD swizzle (neutral but kept; NWG=1004, 8 XCDs)
    int blk;
    {
        const int o   = blockIdx.x;
        const int xcd = o & 7, k = o >> 3;
        const int q = NWG / 8, r = NWG % 8;   // 125, 4
        blk = (xcd < r ? xcd * (q + 1) : r * (q + 1) + (xcd - r) * q) + k;
    }

    const int b    = blk / NPAIR;
    const int pr   = blk - b * NPAIR;
    const int regA = 2 * pr;
    const int s0hA = regA * R_HOPS;      // combined region = hops s0hA..s0hA+15
    const int j    = threadIdx.x;
    const bool edge = (regA == 0) || (regA == 500);  // blocks containing wsq boundary

    // ---- per-block precompute ----
    float2 tw_pack[4];
    #pragma unroll
    for (int kk = 0; kk < 4; ++kk) {
        int k = j + kk * 256;
        float s, c;
        __sincosf(PI_F * (float)k * (1.0f / (float)M), &s, &c);
        tw_pack[kk] = make_float2(c, s);
    }
    float2 w1s[4];
    #pragma unroll
    for (int st = 1; st <= 4; ++st) {
        int Ns = 1 << (2 * st);
        int jm = j & (Ns - 1);
        float ang = (0.5f * PI_F / (float)Ns) * (float)jm;
        float s1, c1;
        __sincosf(ang, &s1, &c1);
        w1s[st-1] = make_float2(c1, s1);
    }
    float wreg[4][2];
    #pragma unroll
    for (int q = 0; q < 4; ++q) {
        int n = j + q * 256;
        #pragma unroll
        for (int h = 0; h < 2; ++h) {
            int t = 2 * n + h;
            float swv = __sinf((PI_F / (float)FFTN) * (float)t);
            wreg[q][h] = swv * swv * (1.0f / 1024.0f);
        }
    }

    // unified accumulator: thread j owns combined float2 slots {256*s + j}
    float2 Acc[CHOPS];
    #pragma unroll
    for (int s = 0; s < CHOPS; ++s) Acc[s] = make_float2(0.f, 0.f);

    const int fbase = s0hA - 3;          // frame slot it2 = f - fbase, 0..18

    #pragma unroll
    for (int t = 0; t < 10; ++t) {
        const int fA = fbase + 2 * t;    // slot it2 = 2t   -> s = 2t-3+q
        const int fB = fA + 1;           // slot it2 = 2t+1 -> s = 2t-2+q
        const bool vA = (fA >= 0) && (fA < NFRAMES);
        const bool vB = (t < 9) && (fB >= 0) && (fB < NFRAMES);  // t=9 B phantom
        if (!vA && !vB) continue;        // block-uniform skip

        int fAc = fA < 0 ? 0 : (fA > NFRAMES-1 ? NFRAMES-1 : fA);
        int fBc = fB < 0 ? 0 : (fB > NFRAMES-1 ? NFRAMES-1 : fB);

        float a1r[4], a1i[4], b1r[4], b1i[4];
        float a2r[4], a2i[4], b2r[4], b2i[4];
        load_spec(sr, si, b, fAc, j, a1r, a1i, b1r, b1i);
        load_spec(sr, si, b, fBc, j, a2r, a2i, b2r, b2i);

        pack2_st0(buf0, j, tw_pack, a1r, a1i, b1r, b1i, a2r, a2i, b2r, b2i);
        __syncthreads();
        stage4x<1>(buf0, buf1, j, w1s[0]);
        __syncthreads();
        stage4x<2>(buf1, buf0, j, w1s[1]);
        __syncthreads();
        stage4x<3>(buf0, buf1, j, w1s[2]);
        __syncthreads();

        // ---- stage 4 in registers + masked windowed accumulate ----
        {
            float4 v0 = buf1[SW4(j)];
            float4 v1 = buf1[SW4(j + 256)];
            float4 v2 = buf1[SW4(j + 512)];
            float4 v3 = buf1[SW4(j + 768)];
            float2 w1 = w1s[3];
            float2 w2 = cmul(w1, w1);
            float2 w3 = cmul(w2, w1);
            v1 = cmul4(v1, w1); v2 = cmul4(v2, w2); v3 = cmul4(v3, w3);
            float4 t0 = f4add(v0, v2), t1 = f4sub(v0, v2);
            float4 t2 = f4add(v1, v3), t3 = f4sub(v1, v3);
            float4 g[4];
            g[0] = f4add(t0, t2);    // n = j
            g[1] = f4addi(t1, t3);   // n = j+256
            g[2] = f4sub(t0, t2);    // n = j+512
            g[3] = f4subi(t1, t3);   // n = j+768
            if (vA) {
                #pragma unroll
                for (int q = 0; q < 4; ++q) {
                    const int s = 2 * t - 3 + q;       // compile-time
                    if (s >= 0 && s < CHOPS) {
                        Acc[s].x += g[q].x * wreg[q][0];
                        Acc[s].y += g[q].y * wreg[q][1];
                    }
                }
            }
            if (vB) {
                #pragma unroll
                for (int q = 0; q < 4; ++q) {
                    const int s = 2 * t - 2 + q;       // compile-time
                    if (s >= 0 && s < CHOPS) {
                        Acc[s].x += g[q].z * wreg[q][0];
                        Acc[s].y += g[q].w * wreg[q][1];
                    }
                }
            }
        }
        // NO trailing barrier (R16-verified ping-pong argument): next pack
        // writes buf0 only — its last readers (stage3) are behind the stage3
        // barrier; st4's buf1 reads complete before this thread reaches the
        // next pack barrier, which precedes stage1(t+1)'s buf1 writes.
    }

    // ---- epilogue: divide by wsq, coalesced single store per sample ----
    float* outb = out + (size_t)b * OUT_T;
    const int base_u = s0hA * HOP;
    #pragma unroll
    for (int s = 0; s < CHOPS; ++s) {
        int i2 = j + 256 * s;
        int p0 = base_u + 2 * i2 - FFTN / 2;
        int p1 = p0 + 1;
        if ((unsigned)p0 < (unsigned)OUT_T) outb[p0] = Acc[s].x * invw_at(p0, edge);
        if ((unsigned)p1 < (unsigned)OUT_T) outb[p1] = Acc[s].y * invw_at(p1, edge);
    }
}

extern "C" void kernel_launch(void* const* d_in, const int* in_sizes, int n_in,
                              void* d_out, int out_size, void* d_ws, size_t ws_size,
                              hipStream_t stream) {
    const float* sr = (const float*)d_in[0];
    const float* si = (const float*)d_in[1];
    float* out = (float*)d_out;
    istft_pair_kernel<<<NWG, 256, 0, stream>>>(sr, si, out);
}